// Round 2
// baseline (2161.782 us; speedup 1.0000x reference)
//
#include <hip/hip_runtime.h>

// ---------- types ----------
typedef __bf16 bf16x8 __attribute__((ext_vector_type(8)));
typedef float  f32x4  __attribute__((ext_vector_type(4)));

// fp32 -> bf16 round-to-nearest-even (bits)
__device__ __forceinline__ unsigned short f2bf(float f) {
    unsigned int u = __builtin_bit_cast(unsigned int, f);
    u = u + 0x7fffu + ((u >> 16) & 1u);
    return (unsigned short)(u >> 16);
}

__device__ __forceinline__ unsigned short sgnbf(float f) {
    return f > 0.f ? (unsigned short)0x3F80 : (f < 0.f ? (unsigned short)0xBF80 : (unsigned short)0);
}

// async global -> LDS, 16 bytes per lane (wave-uniform LDS base + lane*16)
__device__ __forceinline__ void gload_lds16(const void* g, void* l) {
    __builtin_amdgcn_global_load_lds(
        (const __attribute__((address_space(1))) void*)g,
        (__attribute__((address_space(3))) void*)l,
        16, 0, 0);
}

// ---------- kernel 1: row LayerNorm fp32 -> bf16 (K fixed = 4096) ----------
__global__ __launch_bounds__(256) void ln_kernel(const float* __restrict__ x,
                                                 unsigned short* __restrict__ xn,
                                                 int K) {
    const int row = blockIdx.x;
    const float* xr = x + (size_t)row * K;
    unsigned short* outr = xn + (size_t)row * K;
    const int t = threadIdx.x;

    float4 v[4];
    float sum = 0.f, sumsq = 0.f;
#pragma unroll
    for (int c = 0; c < 4; ++c) {
        float4 vv = reinterpret_cast<const float4*>(xr)[c * 256 + t];
        v[c] = vv;
        sum   += vv.x + vv.y + vv.z + vv.w;
        sumsq += vv.x * vv.x + vv.y * vv.y + vv.z * vv.z + vv.w * vv.w;
    }
    // wave(64) reduce
#pragma unroll
    for (int off = 32; off > 0; off >>= 1) {
        sum   += __shfl_down(sum, off);
        sumsq += __shfl_down(sumsq, off);
    }
    __shared__ float s_a[4], s_b[4];
    const int wave = t >> 6, lane = t & 63;
    if (lane == 0) { s_a[wave] = sum; s_b[wave] = sumsq; }
    __syncthreads();
    if (t == 0) {
        float a = s_a[0] + s_a[1] + s_a[2] + s_a[3];
        float b = s_b[0] + s_b[1] + s_b[2] + s_b[3];
        float mean = a / (float)K;
        float var  = fmaxf((b - a * mean) / (float)(K - 1), 0.f); // unbiased (ddof=1)
        float stdv = sqrtf(var);
        s_a[0] = mean;
        s_b[0] = 1.f / (stdv + 1e-5f);   // torch: (x-mean)/(std+eps)
    }
    __syncthreads();
    const float mean = s_a[0], scale = s_b[0];
#pragma unroll
    for (int c = 0; c < 4; ++c) {
        float4 vv = v[c];
        ushort4 o;
        o.x = f2bf((vv.x - mean) * scale);
        o.y = f2bf((vv.y - mean) * scale);
        o.z = f2bf((vv.z - mean) * scale);
        o.w = f2bf((vv.w - mean) * scale);
        reinterpret_cast<ushort4*>(outr)[c * 256 + t] = o;
    }
}

// ---------- kernel 2: sign(W) fp32 -> bf16 {-1,0,+1} ----------
__global__ __launch_bounds__(256) void sign_kernel(const float* __restrict__ w,
                                                   unsigned short* __restrict__ bw,
                                                   long long n4) {
    long long i = (long long)blockIdx.x * blockDim.x + threadIdx.x;
    const long long stride = (long long)gridDim.x * blockDim.x;
    for (; i < n4; i += stride) {
        float4 v = reinterpret_cast<const float4*>(w)[i];
        ushort4 o;
        o.x = sgnbf(v.x); o.y = sgnbf(v.y); o.z = sgnbf(v.z); o.w = sgnbf(v.w);
        reinterpret_cast<ushort4*>(bw)[i] = o;
    }
}

// ---------- kernel 3: C[M,N] = A[M,K] * B[N,K]^T + bias  (bf16 MFMA, m97 structure) ----------
// 128x128 tile, BK=32, 4 waves (2x2), each wave 64x64 = 4x4 fragments of 16x16x32.
__global__ __launch_bounds__(256) void gemm_bt_kernel(const unsigned short* __restrict__ A,
                                                      const unsigned short* __restrict__ B,
                                                      const float* __restrict__ bias,
                                                      float* __restrict__ C,
                                                      int M, int N, int K) {
    __shared__ __align__(16) unsigned short As[128 * 32];
    __shared__ __align__(16) unsigned short Bs[128 * 32];

    const int t = threadIdx.x;
    const int ntn = N >> 7;

    // bijective XCD swizzle (nwg % 8 == 0 here: 64*128 = 8192)
    const int wg  = blockIdx.x;
    const int cpx = gridDim.x >> 3;
    const int swz = (wg & 7) * cpx + (wg >> 3);
    const int brow = (swz / ntn) << 7;
    const int bcol = (swz % ntn) << 7;

    const int wave = t >> 6, lane = t & 63;
    const int wm = (wave & 1) << 6;     // wave row-origin in tile
    const int wn = (wave >> 1) << 6;    // wave col-origin in tile

    // staging: thread t -> row t/4 (and +64), 8 elements at (t%4)*8
    const int srow = t >> 2;
    const int scol = (t & 3) << 3;
    const size_t aBase = (size_t)(brow + srow) * K + scol;
    const size_t bBase = (size_t)(bcol + srow) * K + scol;
    unsigned short* lA0 = &As[srow * 32 + scol];
    unsigned short* lA1 = &As[(srow + 64) * 32 + scol];
    unsigned short* lB0 = &Bs[srow * 32 + scol];
    unsigned short* lB1 = &Bs[(srow + 64) * 32 + scol];

    // fragment read coords: A row = lane&15, k = (lane>>4)*8 + j ; B col = lane&15 (B^T symmetric)
    const int fr = lane & 15;
    const int fk = (lane >> 4) << 3;

    f32x4 acc[4][4];
#pragma unroll
    for (int i = 0; i < 4; ++i)
#pragma unroll
        for (int j = 0; j < 4; ++j) acc[i][j] = (f32x4)0.0f;

    const int nk = K >> 5;
    for (int kt = 0; kt < nk; ++kt) {
        const int kof = kt << 5;
        gload_lds16(A + aBase + kof, lA0);
        gload_lds16(A + aBase + (size_t)64 * K + kof, lA1);
        gload_lds16(B + bBase + kof, lB0);
        gload_lds16(B + bBase + (size_t)64 * K + kof, lB1);
        __syncthreads();   // drains vmcnt -> LDS tiles ready

        bf16x8 af[4], bg[4];
#pragma unroll
        for (int i = 0; i < 4; ++i) {
            af[i] = *reinterpret_cast<const bf16x8*>(&As[(wm + i * 16 + fr) * 32 + fk]);
            bg[i] = *reinterpret_cast<const bf16x8*>(&Bs[(wn + i * 16 + fr) * 32 + fk]);
        }
#pragma unroll
        for (int i = 0; i < 4; ++i)
#pragma unroll
            for (int j = 0; j < 4; ++j)
                acc[i][j] = __builtin_amdgcn_mfma_f32_16x16x32_bf16(af[i], bg[j], acc[i][j], 0, 0, 0);
        __syncthreads();   // protect LDS from next-iter staging
    }

    // epilogue: D mapping col = lane&15, row = (lane>>4)*4 + q  [m89-verified]
    const int crow0 = brow + wm + ((lane >> 4) << 2);
    const int ccol0 = bcol + wn + fr;
#pragma unroll
    for (int j = 0; j < 4; ++j) {
        const int c = ccol0 + j * 16;
        const float bb = bias[c];
#pragma unroll
        for (int i = 0; i < 4; ++i) {
            const int r = crow0 + i * 16;
#pragma unroll
            for (int q = 0; q < 4; ++q)
                C[(size_t)(r + q) * N + c] = acc[i][j][q] + bb;
        }
    }
}

// ---------- host ----------
extern "C" void kernel_launch(void* const* d_in, const int* in_sizes, int n_in,
                              void* d_out, int out_size, void* d_ws, size_t ws_size,
                              hipStream_t stream) {
    const float* x    = (const float*)d_in[0];
    const float* w    = (const float*)d_in[1];
    const float* bias = (const float*)d_in[2];
    float* out = (float*)d_out;

    const int dout   = in_sizes[2];              // 16384
    const int din    = in_sizes[1] / dout;       // 4096
    const int tokens = in_sizes[0] / din;        // 8192

    unsigned short* xn = (unsigned short*)d_ws;
    size_t xn_bytes = (size_t)tokens * din * 2;
    unsigned short* bw = (unsigned short*)((char*)d_ws + ((xn_bytes + 255) & ~(size_t)255));

    ln_kernel<<<tokens, 256, 0, stream>>>(x, xn, din);

    const long long n4 = (long long)dout * din / 4;
    sign_kernel<<<2048, 256, 0, stream>>>(w, bw, n4);

    const int nwg = (tokens / 128) * (dout / 128);
    gemm_bt_kernel<<<nwg, 256, 0, stream>>>(xn, bw, bias, out, tokens, dout, din);
}

// Round 3
// 2000.419 us; speedup vs baseline: 1.0807x; 1.0807x over previous
//
#include <hip/hip_runtime.h>

typedef __bf16 bf16x8 __attribute__((ext_vector_type(8)));
typedef float  f32x4  __attribute__((ext_vector_type(4)));

__device__ __forceinline__ unsigned short f2bf(float f) {
    unsigned int u = __builtin_bit_cast(unsigned int, f);
    u = u + 0x7fffu + ((u >> 16) & 1u);
    return (unsigned short)(u >> 16);
}

__device__ __forceinline__ unsigned short sgnbf(float f) {
    return f > 0.f ? (unsigned short)0x3F80 : (f < 0.f ? (unsigned short)0xBF80 : (unsigned short)0);
}

__device__ __forceinline__ void gld16(const unsigned short* g, unsigned short* l) {
    __builtin_amdgcn_global_load_lds(
        (const __attribute__((address_space(1))) void*)g,
        (__attribute__((address_space(3))) void*)l, 16, 0, 0);
}

#define FENCE() __asm__ volatile("" ::: "memory")
#define BAR()   do { FENCE(); __builtin_amdgcn_s_barrier(); FENCE(); } while (0)
#define WAITVM(N) __asm__ volatile("s_waitcnt vmcnt(" #N ")" ::: "memory")

// ---------- kernel 1: row LayerNorm fp32 -> bf16 ----------
__global__ __launch_bounds__(256) void ln_kernel(const float* __restrict__ x,
                                                 unsigned short* __restrict__ xn,
                                                 int K) {
    const int row = blockIdx.x;
    const float* xr = x + (size_t)row * K;
    unsigned short* outr = xn + (size_t)row * K;
    const int t = threadIdx.x;

    float4 v[4];
    float sum = 0.f, sumsq = 0.f;
#pragma unroll
    for (int c = 0; c < 4; ++c) {
        float4 vv = reinterpret_cast<const float4*>(xr)[c * 256 + t];
        v[c] = vv;
        sum   += vv.x + vv.y + vv.z + vv.w;
        sumsq += vv.x * vv.x + vv.y * vv.y + vv.z * vv.z + vv.w * vv.w;
    }
#pragma unroll
    for (int off = 32; off > 0; off >>= 1) {
        sum   += __shfl_down(sum, off);
        sumsq += __shfl_down(sumsq, off);
    }
    __shared__ float s_a[4], s_b[4];
    const int wave = t >> 6, lane = t & 63;
    if (lane == 0) { s_a[wave] = sum; s_b[wave] = sumsq; }
    __syncthreads();
    if (t == 0) {
        float a = s_a[0] + s_a[1] + s_a[2] + s_a[3];
        float b = s_b[0] + s_b[1] + s_b[2] + s_b[3];
        float mean = a / (float)K;
        float var  = fmaxf((b - a * mean) / (float)(K - 1), 0.f);
        float stdv = sqrtf(var);
        s_a[0] = mean;
        s_b[0] = 1.f / (stdv + 1e-5f);
    }
    __syncthreads();
    const float mean = s_a[0], scale = s_b[0];
#pragma unroll
    for (int c = 0; c < 4; ++c) {
        float4 vv = v[c];
        ushort4 o;
        o.x = f2bf((vv.x - mean) * scale);
        o.y = f2bf((vv.y - mean) * scale);
        o.z = f2bf((vv.z - mean) * scale);
        o.w = f2bf((vv.w - mean) * scale);
        reinterpret_cast<ushort4*>(outr)[c * 256 + t] = o;
    }
}

// ---------- kernel 2: sign(W) fp32 -> bf16 {-1,0,+1} ----------
__global__ __launch_bounds__(256) void sign_kernel(const float* __restrict__ w,
                                                   unsigned short* __restrict__ bw,
                                                   long long n4) {
    long long i = (long long)blockIdx.x * blockDim.x + threadIdx.x;
    const long long stride = (long long)gridDim.x * blockDim.x;
    for (; i < n4; i += stride) {
        float4 v = reinterpret_cast<const float4*>(w)[i];
        ushort4 o;
        o.x = sgnbf(v.x); o.y = sgnbf(v.y); o.z = sgnbf(v.z); o.w = sgnbf(v.w);
        reinterpret_cast<ushort4*>(bw)[i] = o;
    }
}

// ---------- kernel 3: 256x256-tile 8-phase bf16 GEMM, C = A * B^T + bias ----------
// A[M,K] bf16 (xn), B[N,K] bf16 (sign(W)), C[M,N] fp32.
// 512 threads = 8 waves (2 row x 4 col), per-wave output 128x64.
// BK=64, double-buffered LDS (128 KiB), XOR swizzle col ^= (row&7)<<3 via
// pre-swizzled global source (linear global_load_lds dest) + swizzled ds_read.
__global__ __launch_bounds__(512, 2) void gemm256_kernel(
    const unsigned short* __restrict__ A,
    const unsigned short* __restrict__ B,
    const float* __restrict__ bias,
    float* __restrict__ C,
    int M, int N, int K) {

    __shared__ unsigned short As[2][2][128 * 64];
    __shared__ unsigned short Bs[2][2][128 * 64];

    const int t = threadIdx.x;
    const int lane = t & 63;
    const int wave = t >> 6;
    const int wr = wave >> 2;   // 0..1 (row)
    const int wc = wave & 3;    // 0..3 (col)

    // --- tile coordinates: XCD swizzle + per-XCD 4-row-band, tn-major ---
    const int ntm = M >> 8, ntn = N >> 8;
    const int wg  = blockIdx.x;
    const int cpx = gridDim.x >> 3;
    const int swz = (wg & 7) * cpx + (wg >> 3);
    int tm, tn;
    if ((ntm & 7) == 0) {
        const int bandh = ntm >> 3;
        const int xcd = swz / cpx;
        const int s   = swz - xcd * cpx;
        tm = xcd * bandh + s % bandh;
        tn = s / bandh;
    } else {
        tm = swz / ntn; tn = swz % ntn;
    }
    const int brow = tm << 8, bcol = tn << 8;

    // --- staging addresses (global source pre-swizzled; LDS dest linear) ---
    const int srow = t >> 3;                         // 0..63 (row within 64-row chunk)
    const int scol = (t & 7) << 3;                   // 0,8,..,56
    const int csrc = scol ^ ((srow & 7) << 3);       // inverse swizzle (involution)
    const size_t aBase = (size_t)(brow + srow) * K + csrc;
    const size_t bBase = (size_t)(bcol + srow) * K + csrc;

#define STAGE_A(DB, H, KT) do { \
    const unsigned short* _g = A + aBase + (size_t)((H) * 128) * K + ((size_t)(KT) << 6); \
    gld16(_g,                 &As[DB][H][t * 8]); \
    gld16(_g + (size_t)64 * K, &As[DB][H][4096 + t * 8]); \
} while (0)
#define STAGE_B(DB, H, KT) do { \
    const unsigned short* _g = B + bBase + (size_t)((H) * 128) * K + ((size_t)(KT) << 6); \
    gld16(_g,                 &Bs[DB][H][t * 8]); \
    gld16(_g + (size_t)64 * K, &Bs[DB][H][4096 + t * 8]); \
} while (0)

    // --- fragment read coords (swizzled) ---
    const int fr = lane & 15;
    const int fk = (lane >> 4) << 3;
    const int c0e = fk        ^ ((fr & 7) << 3);     // k-slice 0
    const int c1e = (32 + fk) ^ ((fr & 7) << 3);     // k-slice 1
    const int lrB0 = ((wc & 1) << 6) + fr;           // B local row base

    bf16x8 a[4][2], b[4][2];
    f32x4 acc[8][4];
#pragma unroll
    for (int i = 0; i < 8; ++i)
#pragma unroll
        for (int j = 0; j < 4; ++j) acc[i][j] = (f32x4)0.0f;

#define READ_A(RI) do { \
    const unsigned short* _ab = &As[cur][wr][0]; \
    _Pragma("unroll") \
    for (int rf = 0; rf < 4; ++rf) { \
        const int _lr = (((RI) * 4 + rf) * 16 + fr) * 64; \
        a[rf][0] = *(const bf16x8*)&_ab[_lr + c0e]; \
        a[rf][1] = *(const bf16x8*)&_ab[_lr + c1e]; \
    } } while (0)
#define READ_B(CI) do { \
    const unsigned short* _bb = &Bs[cur][wc >> 1][0]; \
    _Pragma("unroll") \
    for (int jc = 0; jc < 2; ++jc) { \
        const int _lr = (lrB0 + ((CI) * 2 + jc) * 16) * 64; \
        b[(CI) * 2 + jc][0] = *(const bf16x8*)&_bb[_lr + c0e]; \
        b[(CI) * 2 + jc][1] = *(const bf16x8*)&_bb[_lr + c1e]; \
    } } while (0)
#define MFMA_QUAD(RI, CI) do { \
    __builtin_amdgcn_s_setprio(1); \
    _Pragma("unroll") \
    for (int rf = 0; rf < 4; ++rf) \
    _Pragma("unroll") \
    for (int jc = 0; jc < 2; ++jc) { \
        acc[(RI) * 4 + rf][(CI) * 2 + jc] = __builtin_amdgcn_mfma_f32_16x16x32_bf16( \
            a[rf][0], b[(CI) * 2 + jc][0], acc[(RI) * 4 + rf][(CI) * 2 + jc], 0, 0, 0); \
        acc[(RI) * 4 + rf][(CI) * 2 + jc] = __builtin_amdgcn_mfma_f32_16x16x32_bf16( \
            a[rf][1], b[(CI) * 2 + jc][1], acc[(RI) * 4 + rf][(CI) * 2 + jc], 0, 0, 0); \
    } \
    __builtin_amdgcn_s_setprio(0); \
} while (0)

    // --- prologue: stage tile 0 into buf 0 (8 loads) ---
    STAGE_A(0, 0, 0); STAGE_A(0, 1, 0);
    STAGE_B(0, 0, 0); STAGE_B(0, 1, 0);

    const int nkt = K >> 6;
    int cur = 0;
    for (int kt = 0; kt < nkt - 1; ++kt) {
        const int nxt = cur ^ 1;
        // P0: quad(0,0) — stage next A-half0, wait this tile's 8 loads (2 newer in flight)
        STAGE_A(nxt, 0, kt + 1);
        WAITVM(2);
        BAR();
        READ_A(0);
        READ_B(0);
        MFMA_QUAD(0, 0);
        BAR();
        // P1: quad(0,1)
        READ_B(1);
        STAGE_A(nxt, 1, kt + 1);
        BAR();
        MFMA_QUAD(0, 1);
        BAR();
        // P2: quad(1,0)
        READ_A(1);
        STAGE_B(nxt, 0, kt + 1);
        BAR();
        MFMA_QUAD(1, 0);
        BAR();
        // P3: quad(1,1)
        STAGE_B(nxt, 1, kt + 1);
        BAR();
        MFMA_QUAD(1, 1);
        BAR();
        cur = nxt;
    }
    // --- last tile (no prefetch): drain ---
    WAITVM(0);
    BAR();
    READ_A(0);
    READ_B(0);
    MFMA_QUAD(0, 0);
    READ_B(1);
    MFMA_QUAD(0, 1);
    READ_A(1);
    MFMA_QUAD(1, 0);
    MFMA_QUAD(1, 1);

    // --- epilogue: D mapping col = lane&15, row = (lane>>4)*4 + q ---
    const int crow0 = brow + wr * 128 + ((lane >> 4) << 2);
    const int ccol0 = bcol + (wc << 6) + fr;
    float bb[4];
#pragma unroll
    for (int j = 0; j < 4; ++j) bb[j] = bias[ccol0 + j * 16];
#pragma unroll
    for (int i = 0; i < 8; ++i) {
#pragma unroll
        for (int j = 0; j < 4; ++j) {
#pragma unroll
            for (int q = 0; q < 4; ++q)
                C[(size_t)(crow0 + i * 16 + q) * N + ccol0 + j * 16] = acc[i][j][q] + bb[j];
        }
    }
#undef STAGE_A
#undef STAGE_B
#undef READ_A
#undef READ_B
#undef MFMA_QUAD
}

// ---------- host ----------
extern "C" void kernel_launch(void* const* d_in, const int* in_sizes, int n_in,
                              void* d_out, int out_size, void* d_ws, size_t ws_size,
                              hipStream_t stream) {
    const float* x    = (const float*)d_in[0];
    const float* w    = (const float*)d_in[1];
    const float* bias = (const float*)d_in[2];
    float* out = (float*)d_out;

    const int dout   = in_sizes[2];              // 16384
    const int din    = in_sizes[1] / dout;       // 4096
    const int tokens = in_sizes[0] / din;        // 8192

    unsigned short* xn = (unsigned short*)d_ws;
    size_t xn_bytes = (size_t)tokens * din * 2;
    unsigned short* bw = (unsigned short*)((char*)d_ws + ((xn_bytes + 255) & ~(size_t)255));

    ln_kernel<<<tokens, 256, 0, stream>>>(x, xn, din);

    const long long n4 = (long long)dout * din / 4;
    sign_kernel<<<2048, 256, 0, stream>>>(w, bw, n4);

    const int nwg = (tokens / 256) * (dout / 256);
    gemm256_kernel<<<nwg, 512, 0, stream>>>(xn, bw, bias, out, tokens, dout, din);
}